// Round 14
// baseline (304.620 us; speedup 1.0000x reference)
//
#include <hip/hip_runtime.h>
#include <hip/hip_fp16.h>

#define D     2048
#define BLK   512
#define TPB   16
#define EPSV  1e-5f

typedef _Float16 h2 __attribute__((ext_vector_type(2)));

__device__ __forceinline__ unsigned int pkh(float a, float b) {
    return __builtin_bit_cast(unsigned int, __builtin_amdgcn_cvt_pkrtz(a, b));
}
__device__ __forceinline__ h2 ash2(unsigned int u) {
    return __builtin_bit_cast(h2, u);
}

// DPP row_shr:N add (old=0)
template<int CTRL>
__device__ __forceinline__ float dppadd(float x) {
    int y = __builtin_amdgcn_update_dpp(0, __builtin_bit_cast(int, x), CTRL, 0xf, 0xf, false);
    return x + __builtin_bit_cast(float, y);
}
// full wave64 sum; result valid in lanes 15,31,47,63
__device__ __forceinline__ float wave_sum(float x) {
    x += __shfl_xor(x, 32, 64);
    x += __shfl_xor(x, 16, 64);
    x = dppadd<0x111>(x);
    x = dppadd<0x112>(x);
    x = dppadd<0x114>(x);
    x = dppadd<0x118>(x);
    return x;
}

__device__ __forceinline__ float rdlane(float v, int l) {
    return __builtin_bit_cast(float, __builtin_amdgcn_readlane(__builtin_bit_cast(int, v), l));
}

// async global->LDS, 16B per lane; LDS dest = wave-uniform base + lane*16
__device__ __forceinline__ void gld16(const float* g, float* l) {
    __builtin_amdgcn_global_load_lds(
        (const __attribute__((address_space(1))) unsigned int*)g,
        (__attribute__((address_space(3))) unsigned int*)l, 16, 0, 0);
}

// ---- weight prep: Wq[c][p] = packed f16 pair of column c at d={2p,2p+1}; S[c] = sum_d w[c][d]
// c: 0-3 Wb, 4-7 Wm, 8-23 Wr(i*4+j). Grid: 24 blocks x 256 threads.
__global__ __launch_bounds__(256) void wt_kernel(
    const float* __restrict__ Wb, const float* __restrict__ Wm,
    const float* __restrict__ Wr, unsigned int* __restrict__ Wq,
    float* __restrict__ S)
{
    const int c = blockIdx.x;
    const int t = threadIdx.x;
    const float* src;
    int stride;
    if (c < 4)       { src = Wb + c;       stride = 4;  }
    else if (c < 8)  { src = Wm + (c - 4); stride = 4;  }
    else             { src = Wr + (c - 8); stride = 16; }

    float s = 0.f;
    #pragma unroll
    for (int k = 0; k < 4; ++k) {
        int p = t + 256 * k;                    // pair index 0..1023
        float a = src[(2 * p)     * stride];
        float b = src[(2 * p + 1) * stride];
        s += a + b;
        Wq[c * 1024 + p] = pkh(a, b);
    }
    __shared__ float rsum[4];
    #pragma unroll
    for (int off = 32; off; off >>= 1) s += __shfl_xor(s, off, 64);
    if ((t & 63) == 0) rsum[t >> 6] = s;
    __syncthreads();
    if (t == 0) S[c] = rsum[0] + rsum[1] + rsum[2] + rsum[3];
}

__global__ __launch_bounds__(BLK) void hc_kernel(
    const float* __restrict__ lo,      // [tok, D]
    const float* __restrict__ hs,      // [tok, 4, D]
    const float* __restrict__ Bm,      // [1,4]
    const float* __restrict__ Am,      // [4,1]
    const float* __restrict__ Ar,      // [4,4]
    const float* __restrict__ s_alpha, // [4,4]
    const float* __restrict__ s_beta,  // [1,4]
    const unsigned int* __restrict__ Wq, // [24][1024] packed f16 weight pairs
    const float* __restrict__ S,       // [24] column sums
    float* __restrict__ out)           // [tok, 4, D]
{
    __shared__ __align__(16) float hbuf[2][4][D];  // 64 KB double-buffered f32 hidden rows
    __shared__ float Rl[24][4];
    __shared__ float sred[8][2];

    const int tid  = threadIdx.x;
    const int wave = tid >> 6;
    const int lane = tid & 63;
    const long tok0 = (long)blockIdx.x * TPB;
    const uint2* Wq2 = (const uint2*)Wq;           // [24][512]

    // ---- prologue: prefetch token tok0 into buf 0 ----
    {
        const float* g = hs + tok0 * (long)(4 * D) + wave * 1024 + lane * 4;
        float*       l = &hbuf[0][0][0] + wave * 1024;
        #pragma unroll
        for (int k = 0; k < 4; ++k) gld16(g + k * 256, l + k * 256);
    }
    float4 lva = ((const float4*)(lo + tok0 * (long)D))[tid];
    float4 lvb;
    asm volatile("s_waitcnt vmcnt(0)" ::: "memory");
    __syncthreads();

    auto step = [&](int buf, float4& lv, float4& lvn, long tok, bool pf) {
        // ---- prefetch next token (latency hides under P2+combine+P3) ----
        if (pf) {
            const float* g = hs + (tok + 1) * (long)(4 * D) + wave * 1024 + lane * 4;
            float*       l = &hbuf[buf ^ 1][0][0] + wave * 1024;
            #pragma unroll
            for (int k = 0; k < 4; ++k) gld16(g + k * 256, l + k * 256);
            lvn = ((const float4*)(lo + (tok + 1) * (long)D))[tid];
        }

        // ---- P1: stats from LDS (wave pair per row) ----
        {
            const int row = wave >> 1, half = wave & 1;
            const float4* hr = (const float4*)&hbuf[buf][row][half * 1024];
            float s = 0.f, q = 0.f;
            #pragma unroll
            for (int k = 0; k < 4; ++k) {
                float4 v = hr[k * 64 + lane];
                s += v.x + v.y + v.z + v.w;
                q += v.x * v.x + v.y * v.y + v.z * v.z + v.w * v.w;
            }
            s = wave_sum(s);
            q = wave_sum(q);
            if (lane == 15) { sred[wave][0] = s; sred[wave][1] = q; }
        }

        // ---- P2: raw dots R[c][n]; wave owns cols 3w..3w+2, full D ----
        float acc[3][4];
        #pragma unroll
        for (int j = 0; j < 3; ++j)
            #pragma unroll
            for (int n = 0; n < 4; ++n) acc[j][n] = 0.f;
        const int c0 = wave * 3;

        #pragma unroll
        for (int i = 0; i < 8; ++i) {
            int i4 = i * 64 + lane;
            h2 plo[4], phi[4];
            #pragma unroll
            for (int n = 0; n < 4; ++n) {
                float4 v = ((const float4*)hbuf[buf][n])[i4];
                plo[n] = ash2(pkh(v.x, v.y));
                phi[n] = ash2(pkh(v.z, v.w));
            }
            uint2 wv[3];
            #pragma unroll
            for (int j = 0; j < 3; ++j) wv[j] = Wq2[(c0 + j) * 512 + i4];
            #pragma unroll
            for (int j = 0; j < 3; ++j)
                #pragma unroll
                for (int n = 0; n < 4; ++n) {
                    acc[j][n] = __builtin_amdgcn_fdot2(plo[n], ash2(wv[j].x), acc[j][n], false);
                    acc[j][n] = __builtin_amdgcn_fdot2(phi[n], ash2(wv[j].y), acc[j][n], false);
                }
        }
        #pragma unroll
        for (int j = 0; j < 3; ++j)
            #pragma unroll
            for (int n = 0; n < 4; ++n) {
                float v = wave_sum(acc[j][n]);
                if (lane == 15) Rl[c0 + j][n] = v;
            }
        __syncthreads();                   // bar1: Rl + sred ready

        // ---- Combine (per-wave redundant; no extra barrier) ----
        float cv = 0.f;
        if (lane < 24) {
            int c = lane;
            float Sc = S[c];
            float raw = 0.f;
            #pragma unroll
            for (int n = 0; n < 4; ++n) {
                float ss = sred[2 * n][0] + sred[2 * n + 1][0];
                float qq = sred[2 * n][1] + sred[2 * n + 1][1];
                float m   = ss * (1.f / D);
                float var = qq * (1.f / D) - m * m;
                float r   = rsqrtf(var + EPSV);
                raw += r * (Rl[c][n] - m * Sc);
            }
            raw *= 0.25f;
            float t = tanhf(raw);
            if (c < 4)      cv = s_beta[c] * t + Bm[c];
            else if (c < 8) cv = s_alpha[(c - 4) * 4] * t + Am[c - 4];
            else            cv = s_alpha[c - 8] * t + Ar[c - 8];
        }
        float Bd[4], Amd[4], Ard[4][4];
        #pragma unroll
        for (int n = 0; n < 4; ++n) {
            Bd[n]  = rdlane(cv, n);
            Amd[n] = rdlane(cv, 4 + n);
        }
        #pragma unroll
        for (int i = 0; i < 4; ++i)
            #pragma unroll
            for (int j = 0; j < 4; ++j) Ard[i][j] = rdlane(cv, 8 + i * 4 + j);

        // ---- P3: outputs from f32 LDS + prefetched lo ----
        float4 h[4];
        #pragma unroll
        for (int n = 0; n < 4; ++n) h[n] = ((const float4*)hbuf[buf][n])[tid];
        float4* out4 = (float4*)(out + tok * (long)(4 * D));
        float4 mx = {0.f, 0.f, 0.f, 0.f};
        #pragma unroll
        for (int n = 0; n < 4; ++n) {
            mx.x += Amd[n] * h[n].x; mx.y += Amd[n] * h[n].y;
            mx.z += Amd[n] * h[n].z; mx.w += Amd[n] * h[n].w;
        }
        #pragma unroll
        for (int i = 0; i < 4; ++i) {
            float4 o;
            o.x = Bd[i] * lv.x + mx.x;
            o.y = Bd[i] * lv.y + mx.y;
            o.z = Bd[i] * lv.z + mx.z;
            o.w = Bd[i] * lv.w + mx.w;
            #pragma unroll
            for (int j = 0; j < 4; ++j) {
                o.x += Ard[i][j] * h[j].x;
                o.y += Ard[i][j] * h[j].y;
                o.z += Ard[i][j] * h[j].z;
                o.w += Ard[i][j] * h[j].w;
            }
            out4[i * 512 + tid] = o;
        }

        // ---- drain prefetch, flip ----
        asm volatile("s_waitcnt vmcnt(0)" ::: "memory");
        __syncthreads();                   // bar2: next buffer loaded for all waves
    };

    for (int t = 0; t < TPB; t += 2) {
        step(0, lva, lvb, tok0 + t,     true);
        step(1, lvb, lva, tok0 + t + 1, t + 2 < TPB);
    }
}

extern "C" void kernel_launch(void* const* d_in, const int* in_sizes, int n_in,
                              void* d_out, int out_size, void* d_ws, size_t ws_size,
                              hipStream_t stream) {
    const float* lo      = (const float*)d_in[0];
    const float* hs      = (const float*)d_in[1];
    const float* Bm      = (const float*)d_in[2];
    const float* Am      = (const float*)d_in[3];
    const float* Ar      = (const float*)d_in[4];
    const float* s_alpha = (const float*)d_in[5];
    const float* s_beta  = (const float*)d_in[6];
    const float* Wb      = (const float*)d_in[7];
    const float* Wm      = (const float*)d_in[8];
    const float* Wr      = (const float*)d_in[9];
    float* out = (float*)d_out;

    unsigned int* Wq = (unsigned int*)d_ws;                    // 98304 B
    float* S         = (float*)((char*)d_ws + 24 * 1024 * 4);  // 96 B

    wt_kernel<<<24, 256, 0, stream>>>(Wb, Wm, Wr, Wq, S);

    const int tokens = in_sizes[0] / D;            // 8192
    hc_kernel<<<tokens / TPB, BLK, 0, stream>>>(lo, hs, Bm, Am, Ar, s_alpha, s_beta,
                                                Wq, S, out);
}